// Round 7
// baseline (868.325 us; speedup 1.0000x reference)
//
#include <hip/hip_runtime.h>
#include <hip/hip_bf16.h>
#include <math.h>

#define D 256
#define EPS 1e-5f
#define SCAN_NB 256

typedef _Float16 f16;
typedef _Float16 f16x4 __attribute__((ext_vector_type(4)));
typedef _Float16 f16x8 __attribute__((ext_vector_type(8)));
typedef float f32x4v __attribute__((ext_vector_type(4)));

// ---------------------------------------------------------------- CSR build
__global__ void k_count(const int* __restrict__ dst, int* __restrict__ cnt, int E) {
    int e = blockIdx.x * blockDim.x + threadIdx.x;
    if (e < E) atomicAdd(&cnt[dst[e]], 1);
}

__global__ void k_dinv(const int* __restrict__ cnt, float* __restrict__ dinv, int N) {
    int i = blockIdx.x * blockDim.x + threadIdx.x;
    if (i < N) dinv[i] = rsqrtf(1.0f + (float)cnt[i]);
}

__global__ void k_scan_part(const int* __restrict__ cnt, int* __restrict__ row_ptr,
                            int* __restrict__ partial, int N, int C) {
    __shared__ int sdata[256];
    int b = blockIdx.x, t = threadIdx.x;
    int base = b * C;
    int end = base + C; if (end > N) end = N;
    int running = 0;
    for (int ts = base; ts < end; ts += 256) {
        int idx = ts + t;
        int val = (idx < end) ? cnt[idx] : 0;
        sdata[t] = val;
        __syncthreads();
        for (int s = 1; s < 256; s <<= 1) {
            int v = (t >= s) ? sdata[t - s] : 0;
            __syncthreads();
            sdata[t] += v;
            __syncthreads();
        }
        if (idx < end) row_ptr[idx] = running + sdata[t] - val;
        running += sdata[255];
        __syncthreads();
    }
    if (t == 0) partial[b] = running;
}

__global__ void k_scan_off(int* __restrict__ partial) {
    __shared__ int sdata[256];
    int t = threadIdx.x;
    int val = partial[t];
    sdata[t] = val;
    __syncthreads();
    for (int s = 1; s < 256; s <<= 1) {
        int v = (t >= s) ? sdata[t - s] : 0;
        __syncthreads();
        sdata[t] += v;
        __syncthreads();
    }
    partial[t] = sdata[t] - val;
}

__global__ void k_scan_add(int* __restrict__ row_ptr, int* __restrict__ cursor,
                           const int* __restrict__ partial, int N, int C, int E) {
    int i = blockIdx.x * 256 + threadIdx.x;
    if (i < N) {
        int v = row_ptr[i] + partial[i / C];
        row_ptr[i] = v;
        cursor[i]  = v;
    }
    if (i == N) row_ptr[N] = E;
}

__global__ void k_fill(const int* __restrict__ src, const int* __restrict__ dst,
                       const float* __restrict__ dinv, int* __restrict__ cursor,
                       int* __restrict__ col, float* __restrict__ coef, int E) {
    int e = blockIdx.x * blockDim.x + threadIdx.x;
    if (e >= E) return;
    int s = src[e], t = dst[e];
    int slot = atomicAdd(&cursor[t], 1);
    col[slot]  = s;
    coef[slot] = dinv[s] * dinv[t];
}

// ---------------------------------------------------------------- casts / weight prep
__global__ void k_cast(const float* __restrict__ in, f16* __restrict__ o, int n4) {
    int i = blockIdx.x * 256 + threadIdx.x;
    if (i >= n4) return;
    float4 v = ((const float4*)in)[i];
    f16x4 h = {(f16)v.x, (f16)v.y, (f16)v.z, (f16)v.w};
    ((f16x4*)o)[i] = h;
}

// Wt[d][k] = (f16) W[k][d];  W is [K][256]
__global__ void k_prep_w(const float* __restrict__ W, f16* __restrict__ Wt, int K) {
    int idx = blockIdx.x * 256 + threadIdx.x;
    if (idx >= K * 256) return;
    int k = idx >> 8, d = idx & 255;
    Wt[(size_t)d * K + k] = (f16)W[idx];
}

// ---------------------------------------------------------------- MFMA GEMM, 64 rows x 256 cols per block
// outh[N,256] = A[N,K] @ Wt^T; optional fused BN-stats epilogue (column sum/sumsq).
#define KSTEP 32
#define ATS 40
#define BTS 40
__global__ __launch_bounds__(256)
void k_gemm(const f16* __restrict__ A, const f16* __restrict__ Wt,
            f16* __restrict__ outh, int N, int K,
            float* __restrict__ sums, float* __restrict__ sumsq) {
    __shared__ __align__(16) f16 As[64 * ATS];
    __shared__ __align__(16) f16 Bs[256 * BTS];
    __shared__ float cs[256], css[256];
    const int r0 = blockIdx.x * 64;
    const int t = threadIdx.x;
    const int lane = t & 63, wave = t >> 6;
    const int quad = lane >> 4, m = lane & 15;

    f32x4v acc[16];
#pragma unroll
    for (int c = 0; c < 16; ++c) acc[c] = {0.f, 0.f, 0.f, 0.f};

    const int sr = t >> 2;        // 0..63
    const int sc = (t & 3) * 8;   // k-chunk offset (halfs)

    for (int k0 = 0; k0 < K; k0 += KSTEP) {
        uint4 av = make_uint4(0u, 0u, 0u, 0u);
        int gr = r0 + sr;
        if (gr < N) av = *(const uint4*)(A + (size_t)gr * K + k0 + sc);
        *(uint4*)(As + sr * ATS + sc) = av;
#pragma unroll
        for (int j = 0; j < 4; ++j) {
            int brow = j * 64 + sr;
            uint4 bv = *(const uint4*)(Wt + (size_t)brow * K + k0 + sc);
            *(uint4*)(Bs + brow * BTS + sc) = bv;
        }
        __syncthreads();

        f16x8 af = *(const f16x8*)(As + (wave * 16 + m) * ATS + quad * 8);
#pragma unroll
        for (int c = 0; c < 16; ++c) {
            f16x8 bf = *(const f16x8*)(Bs + (c * 16 + m) * BTS + quad * 8);
            acc[c] = __builtin_amdgcn_mfma_f32_16x16x32_f16(af, bf, acc[c], 0, 0, 0);
        }
        __syncthreads();
    }

#pragma unroll
    for (int c = 0; c < 16; ++c) {
#pragma unroll
        for (int r = 0; r < 4; ++r) {
            int row = r0 + wave * 16 + quad * 4 + r;
            if (row < N) outh[(size_t)row * D + c * 16 + m] = (f16)acc[c][r];
        }
    }

    if (sums) {
        // rows >= N contributed exact zeros (A zero-filled) -> safe to include
        cs[t] = 0.f; css[t] = 0.f;
        __syncthreads();
#pragma unroll
        for (int c = 0; c < 16; ++c) {
            int f = c * 16 + m;
            float s = acc[c][0] + acc[c][1] + acc[c][2] + acc[c][3];
            float q = acc[c][0]*acc[c][0] + acc[c][1]*acc[c][1]
                    + acc[c][2]*acc[c][2] + acc[c][3]*acc[c][3];
            atomicAdd(&cs[f], s);
            atomicAdd(&css[f], q);
        }
        __syncthreads();
        atomicAdd(&sums[t], cs[t]);
        atomicAdd(&sumsq[t], css[t]);
    }
}

// ---------------------------------------------------------------- gather, 256-dim f16 rows (layers 1-3)
// wave-per-node, f16x4/lane (512B row), unroll x8; fused self-loop + BN stats (no bias).
__global__ void k_gather(const int* __restrict__ row_ptr, const int* __restrict__ col,
                         const float* __restrict__ coef, const f16* __restrict__ hw,
                         const float* __restrict__ dinv,
                         float* __restrict__ out, float* __restrict__ sums,
                         float* __restrict__ sumsq, int N) {
    const int lane = threadIdx.x & 63;
    const int wave = threadIdx.x >> 6;
    const f16x4* __restrict__ hw4 = (const f16x4*)hw;
    float4* __restrict__ out4 = (float4*)out;

    float4 s4  = make_float4(0.f, 0.f, 0.f, 0.f);
    float4 ss4 = make_float4(0.f, 0.f, 0.f, 0.f);

    int wslot  = blockIdx.x * 4 + wave;
    int wtotal = gridDim.x * 4;
    for (int i = wslot; i < N; i += wtotal) {
        int lo = row_ptr[i];
        int hi = row_ptr[i + 1];
        float di = dinv[i];
        float dd = di * di;
        f16x4 hv = hw4[(size_t)i * 64 + lane];
        float4 acc;
        acc.x = (float)hv[0] * dd;
        acc.y = (float)hv[1] * dd;
        acc.z = (float)hv[2] * dd;
        acc.w = (float)hv[3] * dd;

        int e = lo;
        for (; e + 8 <= hi; e += 8) {
            int   n0 = col[e],     n1 = col[e + 1], n2 = col[e + 2], n3 = col[e + 3];
            int   n4 = col[e + 4], n5 = col[e + 5], n6 = col[e + 6], n7 = col[e + 7];
            float c0 = coef[e],     c1 = coef[e + 1], c2 = coef[e + 2], c3 = coef[e + 3];
            float c4 = coef[e + 4], c5 = coef[e + 5], c6 = coef[e + 6], c7 = coef[e + 7];
            f16x4 r0 = hw4[(size_t)n0 * 64 + lane];
            f16x4 r1 = hw4[(size_t)n1 * 64 + lane];
            f16x4 r2 = hw4[(size_t)n2 * 64 + lane];
            f16x4 r3 = hw4[(size_t)n3 * 64 + lane];
            f16x4 r4 = hw4[(size_t)n4 * 64 + lane];
            f16x4 r5 = hw4[(size_t)n5 * 64 + lane];
            f16x4 r6 = hw4[(size_t)n6 * 64 + lane];
            f16x4 r7 = hw4[(size_t)n7 * 64 + lane];
            acc.x = fmaf((float)r0[0], c0, acc.x); acc.y = fmaf((float)r0[1], c0, acc.y);
            acc.z = fmaf((float)r0[2], c0, acc.z); acc.w = fmaf((float)r0[3], c0, acc.w);
            acc.x = fmaf((float)r1[0], c1, acc.x); acc.y = fmaf((float)r1[1], c1, acc.y);
            acc.z = fmaf((float)r1[2], c1, acc.z); acc.w = fmaf((float)r1[3], c1, acc.w);
            acc.x = fmaf((float)r2[0], c2, acc.x); acc.y = fmaf((float)r2[1], c2, acc.y);
            acc.z = fmaf((float)r2[2], c2, acc.z); acc.w = fmaf((float)r2[3], c2, acc.w);
            acc.x = fmaf((float)r3[0], c3, acc.x); acc.y = fmaf((float)r3[1], c3, acc.y);
            acc.z = fmaf((float)r3[2], c3, acc.z); acc.w = fmaf((float)r3[3], c3, acc.w);
            acc.x = fmaf((float)r4[0], c4, acc.x); acc.y = fmaf((float)r4[1], c4, acc.y);
            acc.z = fmaf((float)r4[2], c4, acc.z); acc.w = fmaf((float)r4[3], c4, acc.w);
            acc.x = fmaf((float)r5[0], c5, acc.x); acc.y = fmaf((float)r5[1], c5, acc.y);
            acc.z = fmaf((float)r5[2], c5, acc.z); acc.w = fmaf((float)r5[3], c5, acc.w);
            acc.x = fmaf((float)r6[0], c6, acc.x); acc.y = fmaf((float)r6[1], c6, acc.y);
            acc.z = fmaf((float)r6[2], c6, acc.z); acc.w = fmaf((float)r6[3], c6, acc.w);
            acc.x = fmaf((float)r7[0], c7, acc.x); acc.y = fmaf((float)r7[1], c7, acc.y);
            acc.z = fmaf((float)r7[2], c7, acc.z); acc.w = fmaf((float)r7[3], c7, acc.w);
        }
        for (; e < hi; ++e) {
            int   sn = col[e];
            float c  = coef[e];
            f16x4 r = hw4[(size_t)sn * 64 + lane];
            acc.x = fmaf((float)r[0], c, acc.x); acc.y = fmaf((float)r[1], c, acc.y);
            acc.z = fmaf((float)r[2], c, acc.z); acc.w = fmaf((float)r[3], c, acc.w);
        }

        out4[(size_t)i * 64 + lane] = acc;
        s4.x += acc.x; s4.y += acc.y; s4.z += acc.z; s4.w += acc.w;
        ss4.x += acc.x * acc.x; ss4.y += acc.y * acc.y;
        ss4.z += acc.z * acc.z; ss4.w += acc.w * acc.w;
    }

    __shared__ float rs[4][256];
    __shared__ float rss[4][256];
    int f = lane * 4;
    rs[wave][f + 0] = s4.x;  rs[wave][f + 1] = s4.y;
    rs[wave][f + 2] = s4.z;  rs[wave][f + 3] = s4.w;
    rss[wave][f + 0] = ss4.x; rss[wave][f + 1] = ss4.y;
    rss[wave][f + 2] = ss4.z; rss[wave][f + 3] = ss4.w;
    __syncthreads();
    int t = threadIdx.x;
    float rsum  = rs[0][t] + rs[1][t] + rs[2][t] + rs[3][t];
    float rsum2 = rss[0][t] + rss[1][t] + rss[2][t] + rss[3][t];
    atomicAdd(&sums[t], rsum);
    atomicAdd(&sumsq[t], rsum2);
}

// ---------------------------------------------------------------- gather, 64-dim f16 rows (layer 0 on X)
// wave-per-node, one f16/lane (128B row), unroll x8. No stats (done in GEMM epilogue).
__global__ void k_gather64(const int* __restrict__ row_ptr, const int* __restrict__ col,
                           const float* __restrict__ coef, const f16* __restrict__ xh,
                           const float* __restrict__ dinv, f16* __restrict__ aggx, int N) {
    const int lane = threadIdx.x & 63;
    const int wave = threadIdx.x >> 6;

    int wslot  = blockIdx.x * 4 + wave;
    int wtotal = gridDim.x * 4;
    for (int i = wslot; i < N; i += wtotal) {
        int lo = row_ptr[i];
        int hi = row_ptr[i + 1];
        float di = dinv[i];
        float acc = (float)xh[(size_t)i * 64 + lane] * (di * di);

        int e = lo;
        for (; e + 8 <= hi; e += 8) {
            int   n0 = col[e],     n1 = col[e + 1], n2 = col[e + 2], n3 = col[e + 3];
            int   n4 = col[e + 4], n5 = col[e + 5], n6 = col[e + 6], n7 = col[e + 7];
            float c0 = coef[e],     c1 = coef[e + 1], c2 = coef[e + 2], c3 = coef[e + 3];
            float c4 = coef[e + 4], c5 = coef[e + 5], c6 = coef[e + 6], c7 = coef[e + 7];
            float r0 = (float)xh[(size_t)n0 * 64 + lane];
            float r1 = (float)xh[(size_t)n1 * 64 + lane];
            float r2 = (float)xh[(size_t)n2 * 64 + lane];
            float r3 = (float)xh[(size_t)n3 * 64 + lane];
            float r4 = (float)xh[(size_t)n4 * 64 + lane];
            float r5 = (float)xh[(size_t)n5 * 64 + lane];
            float r6 = (float)xh[(size_t)n6 * 64 + lane];
            float r7 = (float)xh[(size_t)n7 * 64 + lane];
            acc = fmaf(r0, c0, acc); acc = fmaf(r1, c1, acc);
            acc = fmaf(r2, c2, acc); acc = fmaf(r3, c3, acc);
            acc = fmaf(r4, c4, acc); acc = fmaf(r5, c5, acc);
            acc = fmaf(r6, c6, acc); acc = fmaf(r7, c7, acc);
        }
        for (; e < hi; ++e) {
            float r = (float)xh[(size_t)col[e] * 64 + lane];
            acc = fmaf(r, coef[e], acc);
        }
        aggx[(size_t)i * 64 + lane] = (f16)acc;
    }
}

// ---------------------------------------------------------------- BN + tanh
// fp32 input (gather output), f16 out; last layer: fp32 in place.
__global__ void k_bn_tanh(float* __restrict__ h, const float* __restrict__ sums,
                          const float* __restrict__ sumsq, const float* __restrict__ g,
                          const float* __restrict__ be, float Ninv,
                          f16* __restrict__ hh, int n4, int last) {
    int i = blockIdx.x * blockDim.x + threadIdx.x;
    if (i >= n4) return;
    int d = (i & 63) * 4;
    float4 v = ((float4*)h)[i];
    float sc[4], sh[4];
#pragma unroll
    for (int j = 0; j < 4; ++j) {
        float mu  = sums[d + j] * Ninv;
        float var = sumsq[d + j] * Ninv - mu * mu;
        float s   = g[d + j] * rsqrtf(var + EPS);
        sc[j] = s;
        sh[j] = be[d + j] - mu * s;
    }
    v.x = tanhf(fmaf(v.x, sc[0], sh[0]));
    v.y = tanhf(fmaf(v.y, sc[1], sh[1]));
    v.z = tanhf(fmaf(v.z, sc[2], sh[2]));
    v.w = tanhf(fmaf(v.w, sc[3], sh[3]));
    if (last) {
        ((float4*)h)[i] = v;
    } else {
        f16x4 o = {(f16)v.x, (f16)v.y, (f16)v.z, (f16)v.w};
        ((f16x4*)hh)[i] = o;
    }
}

// f16 input (layer-0 GEMM output), f16 out.
__global__ void k_bn_tanh_h(const f16* __restrict__ h, const float* __restrict__ sums,
                            const float* __restrict__ sumsq, const float* __restrict__ g,
                            const float* __restrict__ be, float Ninv,
                            f16* __restrict__ hh, int n4) {
    int i = blockIdx.x * blockDim.x + threadIdx.x;
    if (i >= n4) return;
    int d = (i & 63) * 4;
    f16x4 v = ((const f16x4*)h)[i];
    f16x4 o;
#pragma unroll
    for (int j = 0; j < 4; ++j) {
        float mu  = sums[d + j] * Ninv;
        float var = sumsq[d + j] * Ninv - mu * mu;
        float s   = g[d + j] * rsqrtf(var + EPS);
        float sh  = be[d + j] - mu * s;
        o[j] = (f16)tanhf(fmaf((float)v[j], s, sh));
    }
    ((f16x4*)hh)[i] = o;
}

// ---------------------------------------------------------------- pooling + output GEMV
__device__ __forceinline__ int lb(const int* __restrict__ a, int n, int v) {
    int lo = 0, hi = n;
    while (lo < hi) {
        int mid = (lo + hi) >> 1;
        if (a[mid] < v) lo = mid + 1; else hi = mid;
    }
    return lo;
}

__global__ void k_pool(const float* __restrict__ h, const int* __restrict__ batch,
                       const float* __restrict__ Wout, const float* __restrict__ bout,
                       float* __restrict__ out, float* __restrict__ hidden, int N) {
    int g = blockIdx.x;
    int d = threadIdx.x;
    int lo = lb(batch, N, g);
    int hi = lb(batch, N, g + 1);
    float mx = -INFINITY, sm = 0.0f;
    for (int i = lo; i < hi; ++i) {
        float v = h[(size_t)i * D + d];
        mx = fmaxf(mx, v);
        sm += v;
    }
    float mean = sm / (float)(hi - lo);
    hidden[(size_t)g * (2 * D) + d] = mx;
    hidden[(size_t)g * (2 * D) + D + d] = mean;

    float p = mx * Wout[d] + mean * Wout[D + d];
    __shared__ float red[256];
    red[d] = p;
    __syncthreads();
    for (int s = 128; s > 0; s >>= 1) {
        if (d < s) red[d] += red[d + s];
        __syncthreads();
    }
    if (d == 0) out[g] = red[0] + bout[0];
}

// ----------------------------------------------------------------
extern "C" void kernel_launch(void* const* d_in, const int* in_sizes, int n_in,
                              void* d_out, int out_size, void* d_ws, size_t ws_size,
                              hipStream_t stream) {
    const float* x          = (const float*)d_in[0];
    const int*   edge_index = (const int*)d_in[1];
    const int*   batch      = (const int*)d_in[2];
    const float* Wl[4] = {(const float*)d_in[4], (const float*)d_in[6],
                          (const float*)d_in[8], (const float*)d_in[10]};
    const float* gl[4]  = {(const float*)d_in[12], (const float*)d_in[14],
                           (const float*)d_in[16], (const float*)d_in[18]};
    const float* bel[4] = {(const float*)d_in[13], (const float*)d_in[15],
                           (const float*)d_in[17], (const float*)d_in[19]};
    const float* Wout = (const float*)d_in[20];
    const float* bout = (const float*)d_in[21];

    const int N = in_sizes[0] / 64;       // 50000
    const int E = in_sizes[1] / 2;        // 800000
    const int B = out_size / (1 + 2 * D); // 1000

    const int* srcv = edge_index;
    const int* dstv = edge_index + E;

    // workspace carve-up
    float* P1      = (float*)d_ws;              // [N,D] fp32 agg / final h
    f16*   hw_h    = (f16*)(P1 + (size_t)N * D);// [N,D] f16 GEMM out
    f16*   hh      = hw_h + (size_t)N * D;      // [N,D] f16 activations
    f16*   xh      = hh + (size_t)N * D;        // [N,64] f16 cast of x
    f16*   aggx    = xh + (size_t)N * 64;       // [N,64] f16 agg(X)
    f16*   Wt      = aggx + (size_t)N * 64;     // [256,256] f16 transposed weights
    float* dinv    = (float*)(Wt + 256 * 256);  // [N]
    float* sums    = dinv + N;                  // [D]
    float* sumsq   = sums + D;                  // [D]
    float* coef    = sumsq + D;                 // [E]
    int*   cnt     = (int*)(coef + E);          // [N]
    int*   row_ptr = cnt + N;                   // [N+1]
    int*   cursor  = row_ptr + N + 1;           // [N]
    int*   col     = cursor + N;                // [E]
    int*   partial = col + E;                   // [SCAN_NB]

    float* out_p    = (float*)d_out;            // [B]
    float* hidden_p = out_p + B;                // [B, 512]

    // ---- CSR build
    hipMemsetAsync(cnt, 0, (size_t)N * sizeof(int), stream);
    k_count<<<(E + 255) / 256, 256, 0, stream>>>(dstv, cnt, E);
    k_dinv<<<(N + 255) / 256, 256, 0, stream>>>(cnt, dinv, N);
    const int C = (N + SCAN_NB - 1) / SCAN_NB;
    k_scan_part<<<SCAN_NB, 256, 0, stream>>>(cnt, row_ptr, partial, N, C);
    k_scan_off<<<1, 256, 0, stream>>>(partial);
    k_scan_add<<<(N + 1 + 255) / 256, 256, 0, stream>>>(row_ptr, cursor, partial, N, C, E);
    k_fill<<<(E + 255) / 256, 256, 0, stream>>>(srcv, dstv, dinv, cursor, col, coef, E);

    // x -> f16
    k_cast<<<(N * 64 / 4 + 255) / 256, 256, 0, stream>>>(x, xh, N * 64 / 4);

    const int gemm_blocks = (N + 63) / 64;
    const int nd4 = N * D / 4;

    // ---- layer 0: agg(X) [64-dim gather] -> GEMM(+stats) -> BN+tanh
    k_gather64<<<2048, 256, 0, stream>>>(row_ptr, col, coef, xh, dinv, aggx, N);
    k_prep_w<<<64, 256, 0, stream>>>(Wl[0], Wt, 64);
    hipMemsetAsync(sums, 0, 2 * D * sizeof(float), stream);
    k_gemm<<<gemm_blocks, 256, 0, stream>>>(aggx, Wt, hw_h, N, 64, sums, sumsq);
    k_bn_tanh_h<<<(nd4 + 255) / 256, 256, 0, stream>>>(
        hw_h, sums, sumsq, gl[0], bel[0], 1.0f / (float)N, hh, nd4);

    // ---- layers 1-3: GEMM -> gather(+stats) -> BN+tanh
    for (int l = 1; l < 4; ++l) {
        k_prep_w<<<256, 256, 0, stream>>>(Wl[l], Wt, 256);
        k_gemm<<<gemm_blocks, 256, 0, stream>>>(hh, Wt, hw_h, N, 256, nullptr, nullptr);
        hipMemsetAsync(sums, 0, 2 * D * sizeof(float), stream);
        k_gather<<<2048, 256, 0, stream>>>(row_ptr, col, coef, hw_h, dinv,
                                           P1, sums, sumsq, N);
        k_bn_tanh<<<(nd4 + 255) / 256, 256, 0, stream>>>(
            P1, sums, sumsq, gl[l], bel[l], 1.0f / (float)N, hh, nd4, l == 3);
    }

    k_pool<<<B, 256, 0, stream>>>(P1, batch, Wout, bout, out_p, hidden_p, N);
}